// Round 7
// baseline (1221.105 us; speedup 1.0000x reference)
//
#include <hip/hip_runtime.h>

#define DEVINL __device__ __forceinline__

static const int NPTS = 2048;

typedef __attribute__((ext_vector_type(8))) short bf16x8;
typedef __attribute__((ext_vector_type(4))) float f32x4;

DEVINL unsigned fenc(float x) {
    int b = __float_as_int(x);
    return (b < 0) ? ~(unsigned)b : ((unsigned)b | 0x80000000u);
}
DEVINL float fdec(unsigned u) {
    return (u & 0x80000000u) ? __int_as_float((int)(u & 0x7fffffffu))
                             : __int_as_float((int)~u);
}
DEVINL unsigned long long u64min(unsigned long long a, unsigned long long b) {
    return (b < a) ? b : a;
}
DEVINL unsigned short f2bf(float x) {  // round-to-nearest-even bf16
    unsigned u = __float_as_uint(x);
    return (unsigned short)((u + 0x7fffu + ((u >> 16) & 1u)) >> 16);
}
DEVINL float bf2f(unsigned short h) { return __uint_as_float(((unsigned)h) << 16); }

// ---------------------------------------------------------------------------
// Exact top-20 of 2048 fp32 values in v[32]/lane (col = lane*4+(j&3)+(j>>2)*256).
// Used by select0 (layer 0, C=3, stays full-fp32).
// ---------------------------------------------------------------------------
DEVINL void topk20(float v[32], unsigned long long* cand, int lane,
                   int* __restrict__ Iout, int outBase) {
    float t16[16];
#pragma unroll
    for (int i = 0; i < 16; ++i) t16[i] = fminf(v[i], v[i + 16]);
#pragma unroll
    for (int i = 0; i < 8; ++i) t16[i] = fminf(t16[i], t16[i + 8]);
#pragma unroll
    for (int i = 0; i < 4; ++i) t16[i] = fminf(t16[i], t16[i + 4]);
    float s = fminf(fminf(t16[0], t16[1]), fminf(t16[2], t16[3]));
#pragma unroll
    for (int k = 2; k <= 64; k <<= 1) {
#pragma unroll
        for (int j = k >> 1; j >= 1; j >>= 1) {
            float o = __shfl_xor(s, j);
            bool keepmin = (((lane & j) == 0) == ((lane & k) == 0));
            s = keepmin ? fminf(s, o) : fmaxf(s, o);
        }
    }
    const float tau = __shfl(s, 19);
    int cnt = 0;
#pragma unroll
    for (int j = 0; j < 32; ++j) {
        bool pass = (v[j] <= tau);
        unsigned long long mask = __ballot(pass);
        if (pass) {
            int pos = cnt + (int)__popcll(mask & ((1ull << lane) - 1ull));
            if (pos < 64) {
                int col = lane * 4 + (j & 3) + ((j >> 2) << 8);
                cand[pos] = ((unsigned long long)fenc(v[j]) << 32) | (unsigned)col;
            }
        }
        cnt += (int)__popcll(mask);
    }
    if (cnt <= 64) {
        unsigned long long key = (lane < cnt) ? cand[lane] : ~0ull;
#pragma unroll
        for (int k = 2; k <= 64; k <<= 1) {
#pragma unroll
            for (int j = k >> 1; j >= 1; j >>= 1) {
                unsigned long long o = __shfl_xor(key, j);
                bool keepmin = (((lane & j) == 0) == ((lane & k) == 0));
                unsigned long long mn = u64min(key, o);
                unsigned long long mx = (key ^ o) ^ mn;
                key = keepmin ? mn : mx;
            }
        }
        if (lane < 20) Iout[outBase + lane] = (int)(unsigned)(key & 0xffffffffu);
    } else {
        unsigned long long vk[32];
#pragma unroll
        for (int j = 0; j < 32; ++j) {
            int col = lane * 4 + (j & 3) + ((j >> 2) << 8);
            vk[j] = ((unsigned long long)fenc(v[j]) << 32) | (unsigned)col;
        }
        unsigned long long last = 0ull;
        for (int it = 0; it < 20; ++it) {
            unsigned long long q16[16];
#pragma unroll
            for (int i = 0; i < 16; ++i) {
                unsigned long long a = (vk[i] > last) ? vk[i] : ~0ull;
                unsigned long long c = (vk[i + 16] > last) ? vk[i + 16] : ~0ull;
                q16[i] = u64min(a, c);
            }
#pragma unroll
            for (int i = 0; i < 8; ++i) q16[i] = u64min(q16[i], q16[i + 8]);
#pragma unroll
            for (int i = 0; i < 4; ++i) q16[i] = u64min(q16[i], q16[i + 4]);
            unsigned long long best = u64min(u64min(q16[0], q16[1]), u64min(q16[2], q16[3]));
#pragma unroll
            for (int off = 32; off >= 1; off >>= 1) {
                unsigned long long o = __shfl_down(best, off);
                best = u64min(best, o);
            }
            best = __shfl(best, 0);
            if (lane == 0) Iout[outBase + it] = (int)(unsigned)(best & 0xffffffffu);
            last = best;
        }
    }
}

// ---------------------------------------------------------------------------
// sqmax: sq[b][m] = sum_c x^2 (ascending-c fma chain — bit-identical to the
// prior rounds' inline sq) + per-batch max(sq) via wave-reduce + atomicMax.
// ---------------------------------------------------------------------------
__global__ __launch_bounds__(256) void sqmax_kernel(const float* __restrict__ X, int bs,
                                                    float* __restrict__ sqOut,
                                                    unsigned* __restrict__ Rsq) {
    const int N = NPTS;
    const int b = blockIdx.y, m = blockIdx.x * 256 + threadIdx.x;
    const float* __restrict__ Xb = X + (size_t)b * bs;
    float s = 0.f;
#pragma unroll 8
    for (int c = 0; c < 64; ++c) { float t = Xb[(size_t)c * N + m]; s = fmaf(t, t, s); }
    sqOut[(b << 11) + m] = s;
    float mx = s;
#pragma unroll
    for (int off = 32; off >= 1; off >>= 1) mx = fmaxf(mx, __shfl_down(mx, off));
    if ((threadIdx.x & 63) == 0) atomicMax(&Rsq[b], __float_as_uint(mx));  // s >= 0
}

// ---------------------------------------------------------------------------
// KNN via bf16x3 MFMA + exact fp32 refine. Block = 512 threads (8 waves), 16
// query rows. Two column passes of 1024; approx D~ = sq[m]-2*(AhBh+AhBl+AlBh)
// written to LDS Dr [16][1028] fp32 (stride 1028 -> 2-way write aliasing,
// free). Each wave owns 2 rows; v[2][2][16] kept in registers. Selection:
// tau21 = 21st of 64 lane-minima (>= approx 21st); cutoff = tau21 + 2*margin,
// margin = 3e-4*|x_n|*Rmax >> max |approx-exact| error (~2^-15*|x_n||x_m|)
// => candidates PROVABLY include the exact top-21 (self included; dropping
// rank-0 reproduces argsort[:,1:21]). Candidates (~25-30) refined with the
// SAME ascending-c fp32 fma chain as prior rounds => bit-identical indices.
// ---------------------------------------------------------------------------
__global__ __launch_bounds__(512) void knnmfma_kernel(
    const unsigned short* __restrict__ HtH, const unsigned short* __restrict__ HtL,
    int hoff, const float* __restrict__ Xf, int bsX,
    const float* __restrict__ sqB, const unsigned* __restrict__ Rsq,
    int* __restrict__ Iout) {
    extern __shared__ char smem[];
    float* Dr = (float*)smem;            // [16][1028] fp32 = 65792 B
    int* cand = (int*)(smem + 65792);    // [16][64]        =  4096 B
    const int N = NPTS, K = 20, DS = 1028;
    const int b = blockIdx.y, n0 = blockIdx.x * 16;
    const int tid = threadIdx.x, wave = tid >> 6, lane = tid & 63;
    const int fr = lane & 15, quad = lane >> 4;
    const float Rmax = sqrtf(__uint_as_float(Rsq[b]));

    // A-fragments for the block's 16 query rows (A[m=lane&15][k=quad*8+j])
    const size_t abase = ((size_t)(b * N + n0 + fr)) * 320 + hoff + quad * 8;
    const bf16x8 aH0 = *(const bf16x8*)&HtH[abase];
    const bf16x8 aH1 = *(const bf16x8*)&HtH[abase + 32];
    const bf16x8 aL0 = *(const bf16x8*)&HtL[abase];
    const bf16x8 aL1 = *(const bf16x8*)&HtL[abase + 32];

    float v[2][2][16];
#pragma unroll
    for (int pass = 0; pass < 2; ++pass) {
#pragma unroll 2
        for (int tt = 0; tt < 8; ++tt) {
            const int m0 = pass * 1024 + wave * 128 + tt * 16;
            const size_t bbase = ((size_t)(b * N + m0 + fr)) * 320 + hoff + quad * 8;
            bf16x8 bH0 = *(const bf16x8*)&HtH[bbase];
            bf16x8 bH1 = *(const bf16x8*)&HtH[bbase + 32];
            bf16x8 bL0 = *(const bf16x8*)&HtL[bbase];
            bf16x8 bL1 = *(const bf16x8*)&HtL[bbase + 32];
            f32x4 acc = (f32x4){0.f, 0.f, 0.f, 0.f};
            acc = __builtin_amdgcn_mfma_f32_16x16x32_bf16(aH0, bH0, acc, 0, 0, 0);
            acc = __builtin_amdgcn_mfma_f32_16x16x32_bf16(aH1, bH1, acc, 0, 0, 0);
            acc = __builtin_amdgcn_mfma_f32_16x16x32_bf16(aH0, bL0, acc, 0, 0, 0);
            acc = __builtin_amdgcn_mfma_f32_16x16x32_bf16(aH1, bL1, acc, 0, 0, 0);
            acc = __builtin_amdgcn_mfma_f32_16x16x32_bf16(aL0, bH0, acc, 0, 0, 0);
            acc = __builtin_amdgcn_mfma_f32_16x16x32_bf16(aL1, bH1, acc, 0, 0, 0);
            const float sqv = sqB[(b << 11) + m0 + fr];
            const int mloc = wave * 128 + tt * 16 + fr;
#pragma unroll
            for (int r = 0; r < 4; ++r)
                Dr[(quad * 4 + r) * DS + mloc] = sqv - 2.f * acc[r];
        }
        __syncthreads();
#pragma unroll
        for (int rr = 0; rr < 2; ++rr) {
            const float* __restrict__ rp = &Dr[(wave * 2 + rr) * DS];
#pragma unroll
            for (int q = 0; q < 4; ++q) {
                float4 x4 = *(const float4*)&rp[lane * 4 + q * 256];
                v[pass][rr][q * 4 + 0] = x4.x; v[pass][rr][q * 4 + 1] = x4.y;
                v[pass][rr][q * 4 + 2] = x4.z; v[pass][rr][q * 4 + 3] = x4.w;
            }
        }
        __syncthreads();  // Dr reused by next pass
    }

    // ---- selection: tau bound + margin, compact candidate columns ----
    int cntk[2];
#pragma unroll
    for (int rr = 0; rr < 2; ++rr) {
        const int nrow = n0 + wave * 2 + rr;
        float lm = v[0][rr][0];
#pragma unroll
        for (int j = 1; j < 16; ++j) lm = fminf(lm, v[0][rr][j]);
#pragma unroll
        for (int j = 0; j < 16; ++j) lm = fminf(lm, v[1][rr][j]);
        float s = lm;
#pragma unroll
        for (int k = 2; k <= 64; k <<= 1) {
#pragma unroll
            for (int j = k >> 1; j >= 1; j >>= 1) {
                float o = __shfl_xor(s, j);
                bool keepmin = (((lane & j) == 0) == ((lane & k) == 0));
                s = keepmin ? fminf(s, o) : fmaxf(s, o);
            }
        }
        const float tau21 = __shfl(s, 20);
        const float sqn = sqB[(b << 11) + nrow];
        const float margin = 3e-4f * sqrtf(fmaxf(sqn, 0.f)) * Rmax + 1e-12f;
        const float cutoff = tau21 + 2.f * margin;
        int cnt = 0;
        int* cl = &cand[(wave * 2 + rr) * 64];
#pragma unroll
        for (int pass = 0; pass < 2; ++pass) {
#pragma unroll
            for (int j = 0; j < 16; ++j) {
                bool p = (v[pass][rr][j] <= cutoff);
                unsigned long long mask = __ballot(p);
                if (p) {
                    int pos = cnt + (int)__popcll(mask & ((1ull << lane) - 1ull));
                    if (pos < 64)
                        cl[pos] = pass * 1024 + lane * 4 + (j & 3) + ((j >> 2) << 8);
                }
                cnt += (int)__popcll(mask);
            }
        }
        cntk[rr] = (cnt > 64) ? 64 : cnt;
    }

    // ---- refine candidates with exact fp32 (ascending-c fma chain) + sort ----
    const float* __restrict__ Xb = Xf + (size_t)b * bsX;
#pragma unroll 1
    for (int rr = 0; rr < 2; ++rr) {
        const int nrow = n0 + wave * 2 + rr;
        const int cnt = cntk[rr];
        unsigned long long key = ~0ull;
        if (lane < cnt) {
            const int m = cand[(wave * 2 + rr) * 64 + lane];
            float acc = 0.f;
#pragma unroll 8
            for (int c = 0; c < 64; ++c)
                acc = fmaf(Xb[(size_t)c * N + nrow], Xb[(size_t)c * N + m], acc);
            const float d = sqB[(b << 11) + m] - 2.f * acc;
            key = ((unsigned long long)fenc(d) << 32) | (unsigned)m;
        }
#pragma unroll
        for (int k = 2; k <= 64; k <<= 1) {
#pragma unroll
            for (int j = k >> 1; j >= 1; j >>= 1) {
                unsigned long long o = __shfl_xor(key, j);
                bool keepmin = (((lane & j) == 0) == ((lane & k) == 0));
                unsigned long long mn = u64min(key, o);
                key = keepmin ? mn : ((key ^ o) ^ mn);
            }
        }
        // rank 0 is the self column (drop-first == argsort[:,1:21])
        if (lane >= 1 && lane < 21)
            Iout[(b * N + nrow) * K + (lane - 1)] = (int)(unsigned)(key & 0xffffffffu);
    }
}

// ---------------------------------------------------------------------------
// select0: layer-0 (C=3) — scores inline, register topk (fp32-exact).
// ---------------------------------------------------------------------------
__global__ __launch_bounds__(256) void select0_kernel(const float* __restrict__ X,
                                                      int* __restrict__ Iout) {
    const int N = NPTS, K = 20;
    __shared__ unsigned long long cand[4][64];
    const int w = threadIdx.x >> 6, lane = threadIdx.x & 63;
    const int rowg = blockIdx.x * 4 + w;
    const int b = rowg >> 11, n = rowg & 2047;
    const float* __restrict__ Xb = X + (size_t)b * 3 * N;
    const float xr = Xb[n], yr = Xb[N + n], zr = Xb[2 * N + n];
    const float INF = __builtin_inff();
    float v[32];
#pragma unroll
    for (int q = 0; q < 8; ++q) {
        const int base = lane * 4 + q * 256;
        const float4 xm = *(const float4*)&Xb[base];
        const float4 ym = *(const float4*)&Xb[N + base];
        const float4 zm = *(const float4*)&Xb[2 * N + base];
        float mx[4] = {xm.x, xm.y, xm.z, xm.w};
        float my[4] = {ym.x, ym.y, ym.z, ym.w};
        float mz[4] = {zm.x, zm.y, zm.z, zm.w};
#pragma unroll
        for (int j = 0; j < 4; ++j) {
            float sq = mx[j] * mx[j] + my[j] * my[j] + mz[j] * mz[j];
            float dot = xr * mx[j] + yr * my[j] + zr * mz[j];
            float d = sq - 2.f * dot;
            v[q * 4 + j] = (base + j == n) ? INF : d;
        }
    }
    topk20(v, &cand[w][0], lane, Iout, (b * N + n) * K);
}

// ---------------------------------------------------------------------------
// U/T GEMMs (unchanged).
// ---------------------------------------------------------------------------
template<int F, int C>
__global__ __launch_bounds__(256) void ut_kernel(const float* __restrict__ X, int bs,
                                                 const float* __restrict__ W,
                                                 const float* __restrict__ bias,
                                                 float* __restrict__ U, float* __restrict__ T) {
    const int N = NPTS;
    __shared__ float Ws2[64][C + 1];
    __shared__ float Wsd[64][C + 1];
    const int n0 = blockIdx.x * 64, f0 = blockIdx.y * 64, b = blockIdx.z;
    const int tid = threadIdx.x;
    for (int i = tid; i < 64 * C; i += 256) {
        int ff = i / C, c = i - ff * C;
        float w1 = W[(f0 + ff) * (2 * C) + c];
        float w2 = W[(f0 + ff) * (2 * C) + C + c];
        Ws2[ff][c] = w2;
        Wsd[ff][c] = w1 - w2;
    }
    __syncthreads();
    const int nt = tid & 15, fg = tid >> 4;
    const float* __restrict__ Xb = X + (size_t)b * bs;
    float au[4][4], av[4][4];
#pragma unroll
    for (int i = 0; i < 4; ++i)
#pragma unroll
        for (int j = 0; j < 4; ++j) { au[i][j] = 0.f; av[i][j] = 0.f; }
#pragma unroll 4
    for (int c = 0; c < C; ++c) {
        const float4 xv = *(const float4*)&Xb[(size_t)c * N + n0 + nt * 4];
#pragma unroll
        for (int fi = 0; fi < 4; ++fi) {
            float w2v = Ws2[fg * 4 + fi][c];
            float wdv = Wsd[fg * 4 + fi][c];
            au[fi][0] += w2v * xv.x; au[fi][1] += w2v * xv.y;
            au[fi][2] += w2v * xv.z; au[fi][3] += w2v * xv.w;
            av[fi][0] += wdv * xv.x; av[fi][1] += wdv * xv.y;
            av[fi][2] += wdv * xv.z; av[fi][3] += wdv * xv.w;
        }
    }
#pragma unroll
    for (int ni = 0; ni < 4; ++ni) {
        int n = n0 + nt * 4 + ni;
        float4 uv = make_float4(au[0][ni], au[1][ni], au[2][ni], au[3][ni]);
        *(float4*)&U[((size_t)b * N + n) * F + f0 + fg * 4] = uv;
    }
#pragma unroll
    for (int fi = 0; fi < 4; ++fi) {
        int f = f0 + fg * 4 + fi;
        float bv = bias[f];
        float4 tv = make_float4(av[fi][0] + bv, av[fi][1] + bv, av[fi][2] + bv, av[fi][3] + bv);
        *(float4*)&T[((size_t)b * F + f) * N + n0 + nt * 4] = tv;
    }
}

// ---------------------------------------------------------------------------
// Gather-max: block = 32 points x 8 f-groups. Writes fp32 Hc slice (optional)
// AND bf16 hi/lo into Ht[b][n][320] at column offset hoff.
// ---------------------------------------------------------------------------
template<int F, bool WRITE_F32>
__global__ __launch_bounds__(256) void gathermax_kernel(const float* __restrict__ U,
                                                        const float* __restrict__ T,
                                                        const int* __restrict__ idx,
                                                        float* __restrict__ Y, int bsY,
                                                        unsigned short* __restrict__ HtH,
                                                        unsigned short* __restrict__ HtL,
                                                        int hoff) {
    const int N = NPTS, K = 20, FG = F / 8;
    __shared__ int sidx[32 * 20];
    const int b = blockIdx.y, n0 = blockIdx.x * 32, tid = threadIdx.x;
    const int p = tid >> 3, fg = tid & 7;
    for (int t = tid; t < 32 * K; t += 256) sidx[t] = idx[(b * N + n0) * K + t];
    __syncthreads();
    const int n = n0 + p;
    const float* __restrict__ Ub = U + (size_t)b * N * F;
    const int fbase = fg * FG;
    float mx[FG];
#pragma unroll
    for (int i = 0; i < FG; ++i) mx[i] = -__builtin_inff();
#pragma unroll 4
    for (int j = 0; j < K; ++j) {
        const int r = sidx[p * K + j];
        const float4* up = (const float4*)&Ub[(size_t)r * F + fbase];
#pragma unroll
        for (int q = 0; q < FG / 4; ++q) {
            float4 a = up[q];
            mx[q * 4 + 0] = fmaxf(mx[q * 4 + 0], a.x);
            mx[q * 4 + 1] = fmaxf(mx[q * 4 + 1], a.y);
            mx[q * 4 + 2] = fmaxf(mx[q * 4 + 2], a.z);
            mx[q * 4 + 3] = fmaxf(mx[q * 4 + 3], a.w);
        }
    }
    float val[FG];
#pragma unroll
    for (int i = 0; i < FG; ++i) {
        const int f = fbase + i;
        val[i] = T[((size_t)b * F + f) * N + n] + mx[i];
        if (WRITE_F32) Y[(size_t)b * bsY + (size_t)f * N + n] = val[i];
    }
    unsigned short hs[FG], ls[FG];
#pragma unroll
    for (int i = 0; i < FG; ++i) {
        unsigned short h = f2bf(val[i]);
        hs[i] = h;
        ls[i] = f2bf(val[i] - bf2f(h));
    }
    const size_t hb = ((size_t)b * N + n) * 320 + hoff + fbase;
#pragma unroll
    for (int q = 0; q < FG / 8; ++q) {
        *(int4*)&HtH[hb + q * 8] = *(const int4*)&hs[q * 8];
        *(int4*)&HtL[hb + q * 8] = *(const int4*)&ls[q * 8];
    }
}

// ---------------------------------------------------------------------------
// conv0_w -> bf16 hi/lo split.
// ---------------------------------------------------------------------------
__global__ __launch_bounds__(256) void wsplit_kernel(const float* __restrict__ W,
                                                     unsigned short* __restrict__ WH,
                                                     unsigned short* __restrict__ WL) {
    const int e = blockIdx.x * 256 + threadIdx.x;
    float w = W[e];
    unsigned short h = f2bf(w);
    WH[e] = h;
    WL[e] = f2bf(w - bf2f(h));
}

// ---------------------------------------------------------------------------
// conv0 + global max via bf16x3 MFMA (unchanged, HW-verified in round 5).
// ---------------------------------------------------------------------------
__global__ __launch_bounds__(256) void conv0mfma_kernel(const unsigned short* __restrict__ HtH,
                                                        const unsigned short* __restrict__ HtL,
                                                        const unsigned short* __restrict__ WH,
                                                        const unsigned short* __restrict__ WL,
                                                        unsigned* __restrict__ M) {
    const int N = NPTS;
    __shared__ unsigned short HsH[64][40], HsL[64][40], WsH[128][40], WsL[128][40];
    const int n0 = blockIdx.x * 64, f0 = blockIdx.y * 128, b = blockIdx.z;
    const int tid = threadIdx.x;
    const int wave = tid >> 6, lane = tid & 63;
    const int wm = wave & 1, wf = wave >> 1;
    const int row = lane & 15, quad = lane >> 4;
    f32x4 acc[2][4];
#pragma unroll
    for (int i = 0; i < 2; ++i)
#pragma unroll
        for (int j = 0; j < 4; ++j) acc[i][j] = (f32x4){0.f, 0.f, 0.f, 0.f};

    const int hn = tid >> 2, hq = tid & 3;
    const int wfr = tid >> 1, wq = tid & 1;

    for (int c0 = 0; c0 < 320; c0 += 32) {
        {
            const size_t src = ((size_t)b * N + n0 + hn) * 320 + c0 + hq * 8;
            *(int4*)&HsH[hn][hq * 8] = *(const int4*)&HtH[src];
            *(int4*)&HsL[hn][hq * 8] = *(const int4*)&HtL[src];
        }
        {
            const size_t src = (size_t)(f0 + wfr) * 320 + c0 + wq * 16;
            *(int4*)&WsH[wfr][wq * 16]     = *(const int4*)&WH[src];
            *(int4*)&WsH[wfr][wq * 16 + 8] = *(const int4*)&WH[src + 8];
            *(int4*)&WsL[wfr][wq * 16]     = *(const int4*)&WL[src];
            *(int4*)&WsL[wfr][wq * 16 + 8] = *(const int4*)&WL[src + 8];
        }
        __syncthreads();
        bf16x8 aH[2], aL[2];
#pragma unroll
        for (int mt = 0; mt < 2; ++mt) {
            aH[mt] = *(const bf16x8*)&HsH[wm * 32 + mt * 16 + row][quad * 8];
            aL[mt] = *(const bf16x8*)&HsL[wm * 32 + mt * 16 + row][quad * 8];
        }
#pragma unroll
        for (int nt = 0; nt < 4; ++nt) {
            bf16x8 bH = *(const bf16x8*)&WsH[wf * 64 + nt * 16 + row][quad * 8];
            bf16x8 bL = *(const bf16x8*)&WsL[wf * 64 + nt * 16 + row][quad * 8];
#pragma unroll
            for (int mt = 0; mt < 2; ++mt) {
                acc[mt][nt] = __builtin_amdgcn_mfma_f32_16x16x32_bf16(aH[mt], bH, acc[mt][nt], 0, 0, 0);
                acc[mt][nt] = __builtin_amdgcn_mfma_f32_16x16x32_bf16(aH[mt], bL, acc[mt][nt], 0, 0, 0);
                acc[mt][nt] = __builtin_amdgcn_mfma_f32_16x16x32_bf16(aL[mt], bH, acc[mt][nt], 0, 0, 0);
            }
        }
        __syncthreads();
    }
#pragma unroll
    for (int nt = 0; nt < 4; ++nt) {
        float m = acc[0][nt][0];
#pragma unroll
        for (int r = 1; r < 4; ++r) m = fmaxf(m, acc[0][nt][r]);
#pragma unroll
        for (int r = 0; r < 4; ++r) m = fmaxf(m, acc[1][nt][r]);
        m = fmaxf(m, __shfl_down(m, 16));
        m = fmaxf(m, __shfl_down(m, 32));
        if (quad == 0)
            atomicMax(&M[(b << 10) + f0 + wf * 64 + nt * 16 + row], fenc(m));
    }
}

// ---------------------------------------------------------------------------
// Fused head (unchanged).
// ---------------------------------------------------------------------------
__global__ __launch_bounds__(256) void fc_kernel(const unsigned* __restrict__ M,
    const float* __restrict__ cb, const float* __restrict__ cs, const float* __restrict__ ct,
    const float* __restrict__ w0, const float* __restrict__ b0, const float* __restrict__ s0, const float* __restrict__ t0,
    const float* __restrict__ w1, const float* __restrict__ b1, const float* __restrict__ s1, const float* __restrict__ t1,
    const float* __restrict__ w2, const float* __restrict__ b2, const float* __restrict__ s2, const float* __restrict__ t2,
    float* __restrict__ out) {
    __shared__ float g0[1024], g1[512], g2[256];
    const int b = blockIdx.x, tid = threadIdx.x;
    for (int f = tid; f < 1024; f += 256) {
        float z = fdec(M[b * 1024 + f]);
        float g = cs[f] * (z + cb[f]) + ct[f];
        g0[f] = fmaxf(g, 0.f);
    }
    __syncthreads();
    for (int f = tid; f < 512; f += 256) {
        const float4* wp = (const float4*)(w0 + (size_t)f * 1024);
        float acc = 0.f;
#pragma unroll 4
        for (int c = 0; c < 256; ++c) {
            float4 wv = wp[c];
            float4 gv = *(const float4*)&g0[c * 4];
            acc += wv.x * gv.x + wv.y * gv.y + wv.z * gv.z + wv.w * gv.w;
        }
        float g = s0[f] * (acc + b0[f]) + t0[f];
        g1[f] = fmaxf(g, 0.f);
    }
    __syncthreads();
    if (tid < 256) {
        const float4* wp = (const float4*)(w1 + (size_t)tid * 512);
        float acc = 0.f;
#pragma unroll 4
        for (int c = 0; c < 128; ++c) {
            float4 wv = wp[c];
            float4 gv = *(const float4*)&g1[c * 4];
            acc += wv.x * gv.x + wv.y * gv.y + wv.z * gv.z + wv.w * gv.w;
        }
        float g = s1[tid] * (acc + b1[tid]) + t1[tid];
        g2[tid] = fmaxf(g, 0.f);
    }
    __syncthreads();
    if (tid < 40) {
        const float4* wp = (const float4*)(w2 + (size_t)tid * 256);
        float acc = 0.f;
#pragma unroll 4
        for (int c = 0; c < 64; ++c) {
            float4 wv = wp[c];
            float4 gv = *(const float4*)&g2[c * 4];
            acc += wv.x * gv.x + wv.y * gv.y + wv.z * gv.z + wv.w * gv.w;
        }
        float g = s2[tid] * (acc + b2[tid]) + t2[tid];
        out[b * 40 + tid] = fmaxf(g, 0.f);
    }
}

// ---------------------------------------------------------------------------
extern "C" void kernel_launch(void* const* d_in, const int* in_sizes, int n_in,
                              void* d_out, int out_size, void* d_ws, size_t ws_size,
                              hipStream_t stream) {
    const float* x       = (const float*)d_in[0];
    const float* ec0_w   = (const float*)d_in[1];
    const float* ec0_b   = (const float*)d_in[2];
    const float* ec1_w   = (const float*)d_in[3];
    const float* ec1_b   = (const float*)d_in[4];
    const float* ec2_w   = (const float*)d_in[5];
    const float* ec2_b   = (const float*)d_in[6];
    const float* ec3_w   = (const float*)d_in[7];
    const float* ec3_b   = (const float*)d_in[8];
    const float* conv0_w = (const float*)d_in[9];
    const float* conv0_b = (const float*)d_in[10];
    const float* conv0_s = (const float*)d_in[11];
    const float* conv0_t = (const float*)d_in[12];
    const float* fc0_w   = (const float*)d_in[13];
    const float* fc0_b   = (const float*)d_in[14];
    const float* fc0_s   = (const float*)d_in[15];
    const float* fc0_t   = (const float*)d_in[16];
    const float* fc1_w   = (const float*)d_in[17];
    const float* fc1_b   = (const float*)d_in[18];
    const float* fc1_s   = (const float*)d_in[19];
    const float* fc1_t   = (const float*)d_in[20];
    const float* fc2_w   = (const float*)d_in[21];
    const float* fc2_b   = (const float*)d_in[22];
    const float* fc2_s   = (const float*)d_in[23];
    const float* fc2_t   = (const float*)d_in[24];
    float* out = (float*)d_out;

    char* ws = (char*)d_ws;
    const int B = 16, N = NPTS;
    float* Hc   = (float*)(ws + 0);            // [16][320][2048]  41,943,040 B
    float* U    = (float*)(ws + 41943040);     // [16][2048][128]  16,777,216 B
    float* T    = (float*)(ws + 58720256);     // [16][128][2048]  16,777,216 B
    int*   I    = (int*)  (ws + 75497472);     // [16][2048][20]    2,621,440 B
    unsigned* M = (unsigned*)(ws + 78118912);  // [16][1024]           65,536 B
    unsigned short* W_hi = (unsigned short*)(ws + 78184448);  //  655,360 B
    unsigned short* W_lo = (unsigned short*)(ws + 78839808);  //  655,360 B
    unsigned short* HtH  = (unsigned short*)(ws + 79495168);  // [16][2048][320] 20,971,520 B
    unsigned short* HtL  = (unsigned short*)(ws + 100466688); // [16][2048][320] 20,971,520 B
    float* sqb  = (float*)(ws + 121438208);    // [16][2048]          131,072 B
    unsigned* Rsq = (unsigned*)(ws + 121569280); // [16]                   64 B
    // end: 121,569,344 B

    (void)hipFuncSetAttribute((const void*)knnmfma_kernel,
                              hipFuncAttributeMaxDynamicSharedMemorySize, 69888);

    dim3 blk(256);
    const int bsX0 = 3 * N, bsH = 320 * N;

    wsplit_kernel<<<dim3(1024 * 320 / 256), blk, 0, stream>>>(conv0_w, W_hi, W_lo);

    // ---- Layer 0 (C=3 -> F=64) ----
    select0_kernel<<<dim3(B * N / 4), blk, 0, stream>>>(x, I);
    ut_kernel<64, 3><<<dim3(N / 64, 1, B), blk, 0, stream>>>(x, bsX0, ec0_w, ec0_b, U, T);
    gathermax_kernel<64, true><<<dim3(N / 32, B), blk, 0, stream>>>(U, T, I, Hc, bsH, HtH, HtL, 0);

    // ---- Layers 1..3 (C=64): MFMA-approx KNN + exact refine ----
    const float* Xin[3] = {Hc, Hc + (size_t)64 * N, Hc + (size_t)128 * N};
    const float* ecw[3] = {ec1_w, ec2_w, ec3_w};
    const float* ecb[3] = {ec1_b, ec2_b, ec3_b};
    for (int L = 0; L < 3; ++L) {
        (void)hipMemsetAsync(Rsq, 0, B * sizeof(unsigned), stream);
        sqmax_kernel<<<dim3(N / 256, B), blk, 0, stream>>>(Xin[L], bsH, sqb, Rsq);
        knnmfma_kernel<<<dim3(N / 16, B), dim3(512), 69888, stream>>>(
            HtH, HtL, 64 * L, Xin[L], bsH, sqb, Rsq, I);
        if (L < 2) {
            ut_kernel<64, 64><<<dim3(N / 64, 1, B), blk, 0, stream>>>(Xin[L], bsH, ecw[L], ecb[L], U, T);
            gathermax_kernel<64, true><<<dim3(N / 32, B), blk, 0, stream>>>(
                U, T, I, Hc + (size_t)(64 * (L + 1)) * N, bsH, HtH, HtL, 64 * (L + 1));
        } else {
            ut_kernel<128, 64><<<dim3(N / 64, 2, B), blk, 0, stream>>>(Xin[L], bsH, ecw[L], ecb[L], U, T);
            gathermax_kernel<128, false><<<dim3(N / 32, B), blk, 0, stream>>>(
                U, T, I, Hc + (size_t)192 * N, bsH, HtH, HtL, 192);
        }
    }

    // ---- conv0 + global max (bf16x3 MFMA) ----
    (void)hipMemsetAsync(M, 0, B * 1024 * sizeof(unsigned), stream);
    conv0mfma_kernel<<<dim3(N / 64, 1024 / 128, B), blk, 0, stream>>>(HtH, HtL, W_hi, W_lo, M);

    // ---- head ----
    fc_kernel<<<dim3(B), blk, 0, stream>>>(M, conv0_b, conv0_s, conv0_t,
                                           fc0_w, fc0_b, fc0_s, fc0_t,
                                           fc1_w, fc1_b, fc1_s, fc1_t,
                                           fc2_w, fc2_b, fc2_s, fc2_t, out);
}

// Round 8
// 1058.383 us; speedup vs baseline: 1.1537x; 1.1537x over previous
//
#include <hip/hip_runtime.h>

#define DEVINL __device__ __forceinline__

static const int NPTS = 2048;

typedef __attribute__((ext_vector_type(8))) short bf16x8;
typedef __attribute__((ext_vector_type(4))) float f32x4;

DEVINL unsigned fenc(float x) {
    int b = __float_as_int(x);
    return (b < 0) ? ~(unsigned)b : ((unsigned)b | 0x80000000u);
}
DEVINL float fdec(unsigned u) {
    return (u & 0x80000000u) ? __int_as_float((int)(u & 0x7fffffffu))
                             : __int_as_float((int)~u);
}
DEVINL unsigned long long u64min(unsigned long long a, unsigned long long b) {
    return (b < a) ? b : a;
}
DEVINL unsigned short f2bf(float x) {  // round-to-nearest-even bf16
    unsigned u = __float_as_uint(x);
    return (unsigned short)((u + 0x7fffu + ((u >> 16) & 1u)) >> 16);
}
DEVINL float bf2f(unsigned short h) { return __uint_as_float(((unsigned)h) << 16); }

// ---------------------------------------------------------------------------
// Exact top-20 of 2048 fp32 values in v[32]/lane (col = lane*4+(j&3)+(j>>2)*256).
// Used by select0 (layer 0, C=3, stays full-fp32).
// ---------------------------------------------------------------------------
DEVINL void topk20(float v[32], unsigned long long* cand, int lane,
                   int* __restrict__ Iout, int outBase) {
    float t16[16];
#pragma unroll
    for (int i = 0; i < 16; ++i) t16[i] = fminf(v[i], v[i + 16]);
#pragma unroll
    for (int i = 0; i < 8; ++i) t16[i] = fminf(t16[i], t16[i + 8]);
#pragma unroll
    for (int i = 0; i < 4; ++i) t16[i] = fminf(t16[i], t16[i + 4]);
    float s = fminf(fminf(t16[0], t16[1]), fminf(t16[2], t16[3]));
#pragma unroll
    for (int k = 2; k <= 64; k <<= 1) {
#pragma unroll
        for (int j = k >> 1; j >= 1; j >>= 1) {
            float o = __shfl_xor(s, j);
            bool keepmin = (((lane & j) == 0) == ((lane & k) == 0));
            s = keepmin ? fminf(s, o) : fmaxf(s, o);
        }
    }
    const float tau = __shfl(s, 19);
    int cnt = 0;
#pragma unroll
    for (int j = 0; j < 32; ++j) {
        bool pass = (v[j] <= tau);
        unsigned long long mask = __ballot(pass);
        if (pass) {
            int pos = cnt + (int)__popcll(mask & ((1ull << lane) - 1ull));
            if (pos < 64) {
                int col = lane * 4 + (j & 3) + ((j >> 2) << 8);
                cand[pos] = ((unsigned long long)fenc(v[j]) << 32) | (unsigned)col;
            }
        }
        cnt += (int)__popcll(mask);
    }
    if (cnt <= 64) {
        unsigned long long key = (lane < cnt) ? cand[lane] : ~0ull;
#pragma unroll
        for (int k = 2; k <= 64; k <<= 1) {
#pragma unroll
            for (int j = k >> 1; j >= 1; j >>= 1) {
                unsigned long long o = __shfl_xor(key, j);
                bool keepmin = (((lane & j) == 0) == ((lane & k) == 0));
                unsigned long long mn = u64min(key, o);
                unsigned long long mx = (key ^ o) ^ mn;
                key = keepmin ? mn : mx;
            }
        }
        if (lane < 20) Iout[outBase + lane] = (int)(unsigned)(key & 0xffffffffu);
    } else {
        unsigned long long vk[32];
#pragma unroll
        for (int j = 0; j < 32; ++j) {
            int col = lane * 4 + (j & 3) + ((j >> 2) << 8);
            vk[j] = ((unsigned long long)fenc(v[j]) << 32) | (unsigned)col;
        }
        unsigned long long last = 0ull;
        for (int it = 0; it < 20; ++it) {
            unsigned long long q16[16];
#pragma unroll
            for (int i = 0; i < 16; ++i) {
                unsigned long long a = (vk[i] > last) ? vk[i] : ~0ull;
                unsigned long long c = (vk[i + 16] > last) ? vk[i + 16] : ~0ull;
                q16[i] = u64min(a, c);
            }
#pragma unroll
            for (int i = 0; i < 8; ++i) q16[i] = u64min(q16[i], q16[i + 8]);
#pragma unroll
            for (int i = 0; i < 4; ++i) q16[i] = u64min(q16[i], q16[i + 4]);
            unsigned long long best = u64min(u64min(q16[0], q16[1]), u64min(q16[2], q16[3]));
#pragma unroll
            for (int off = 32; off >= 1; off >>= 1) {
                unsigned long long o = __shfl_down(best, off);
                best = u64min(best, o);
            }
            best = __shfl(best, 0);
            if (lane == 0) Iout[outBase + it] = (int)(unsigned)(best & 0xffffffffu);
            last = best;
        }
    }
}

// ---------------------------------------------------------------------------
// sqmax: sq[b][m] = sum_c x^2 (ascending-c fma chain) + per-batch max via
// wave-reduce + atomicMax (values >= 0 so uint compare works).
// ---------------------------------------------------------------------------
__global__ __launch_bounds__(256) void sqmax_kernel(const float* __restrict__ X, int bs,
                                                    float* __restrict__ sqOut,
                                                    unsigned* __restrict__ Rsq) {
    const int N = NPTS;
    const int b = blockIdx.y, m = blockIdx.x * 256 + threadIdx.x;
    const float* __restrict__ Xb = X + (size_t)b * bs;
    float s = 0.f;
#pragma unroll 8
    for (int c = 0; c < 64; ++c) { float t = Xb[(size_t)c * N + m]; s = fmaf(t, t, s); }
    sqOut[(b << 11) + m] = s;
    float mx = s;
#pragma unroll
    for (int off = 32; off >= 1; off >>= 1) mx = fmaxf(mx, __shfl_down(mx, off));
    if ((threadIdx.x & 63) == 0) atomicMax(&Rsq[b], __float_as_uint(mx));
}

// ---------------------------------------------------------------------------
// KNN via bf16x3 MFMA + exact fp32 refine (refine reads the TRANSPOSED
// Xt[b][n][64] — per-candidate 256 B contiguous, query row broadcast; fixes
// R7's 8 KB-strided column reads that caused 66 MB FETCH / latency binding).
// Selection margin logic identical to R7 (passed): cutoff = tau21 + 2*margin,
// margin = 3e-4*|x_n|*Rmax >> bf16x3 approx error -> candidate set provably
// contains exact top-21; refine chain ascending-c fmaf == R7 => same indices.
// ---------------------------------------------------------------------------
__global__ __launch_bounds__(512) void knnmfma_kernel(
    const unsigned short* __restrict__ HtH, const unsigned short* __restrict__ HtL,
    int hoff, const float* __restrict__ Xt,
    const float* __restrict__ sqB, const unsigned* __restrict__ Rsq,
    int* __restrict__ Iout) {
    extern __shared__ char smem[];
    float* Dr = (float*)smem;            // [16][1028] fp32 = 65792 B
    int* cand = (int*)(smem + 65792);    // [16][64]        =  4096 B
    const int N = NPTS, K = 20, DS = 1028;
    const int b = blockIdx.y, n0 = blockIdx.x * 16;
    const int tid = threadIdx.x, wave = tid >> 6, lane = tid & 63;
    const int fr = lane & 15, quad = lane >> 4;
    const float Rmax = sqrtf(__uint_as_float(Rsq[b]));

    // A-fragments for the block's 16 query rows (A[m=lane&15][k=quad*8+j])
    const size_t abase = ((size_t)(b * N + n0 + fr)) * 320 + hoff + quad * 8;
    const bf16x8 aH0 = *(const bf16x8*)&HtH[abase];
    const bf16x8 aH1 = *(const bf16x8*)&HtH[abase + 32];
    const bf16x8 aL0 = *(const bf16x8*)&HtL[abase];
    const bf16x8 aL1 = *(const bf16x8*)&HtL[abase + 32];

    float v[2][2][16];
#pragma unroll
    for (int pass = 0; pass < 2; ++pass) {
#pragma unroll 2
        for (int tt = 0; tt < 8; ++tt) {
            const int m0 = pass * 1024 + wave * 128 + tt * 16;
            const size_t bbase = ((size_t)(b * N + m0 + fr)) * 320 + hoff + quad * 8;
            bf16x8 bH0 = *(const bf16x8*)&HtH[bbase];
            bf16x8 bH1 = *(const bf16x8*)&HtH[bbase + 32];
            bf16x8 bL0 = *(const bf16x8*)&HtL[bbase];
            bf16x8 bL1 = *(const bf16x8*)&HtL[bbase + 32];
            f32x4 acc = (f32x4){0.f, 0.f, 0.f, 0.f};
            acc = __builtin_amdgcn_mfma_f32_16x16x32_bf16(aH0, bH0, acc, 0, 0, 0);
            acc = __builtin_amdgcn_mfma_f32_16x16x32_bf16(aH1, bH1, acc, 0, 0, 0);
            acc = __builtin_amdgcn_mfma_f32_16x16x32_bf16(aH0, bL0, acc, 0, 0, 0);
            acc = __builtin_amdgcn_mfma_f32_16x16x32_bf16(aH1, bL1, acc, 0, 0, 0);
            acc = __builtin_amdgcn_mfma_f32_16x16x32_bf16(aL0, bH0, acc, 0, 0, 0);
            acc = __builtin_amdgcn_mfma_f32_16x16x32_bf16(aL1, bH1, acc, 0, 0, 0);
            const float sqv = sqB[(b << 11) + m0 + fr];
            const int mloc = wave * 128 + tt * 16 + fr;
#pragma unroll
            for (int r = 0; r < 4; ++r)
                Dr[(quad * 4 + r) * DS + mloc] = sqv - 2.f * acc[r];
        }
        __syncthreads();
#pragma unroll
        for (int rr = 0; rr < 2; ++rr) {
            const float* __restrict__ rp = &Dr[(wave * 2 + rr) * DS];
#pragma unroll
            for (int q = 0; q < 4; ++q) {
                float4 x4 = *(const float4*)&rp[lane * 4 + q * 256];
                v[pass][rr][q * 4 + 0] = x4.x; v[pass][rr][q * 4 + 1] = x4.y;
                v[pass][rr][q * 4 + 2] = x4.z; v[pass][rr][q * 4 + 3] = x4.w;
            }
        }
        __syncthreads();  // Dr reused by next pass
    }

    // ---- selection: tau bound + margin, compact candidate columns ----
    int cntk[2];
#pragma unroll
    for (int rr = 0; rr < 2; ++rr) {
        const int nrow = n0 + wave * 2 + rr;
        float lm = v[0][rr][0];
#pragma unroll
        for (int j = 1; j < 16; ++j) lm = fminf(lm, v[0][rr][j]);
#pragma unroll
        for (int j = 0; j < 16; ++j) lm = fminf(lm, v[1][rr][j]);
        float s = lm;
#pragma unroll
        for (int k = 2; k <= 64; k <<= 1) {
#pragma unroll
            for (int j = k >> 1; j >= 1; j >>= 1) {
                float o = __shfl_xor(s, j);
                bool keepmin = (((lane & j) == 0) == ((lane & k) == 0));
                s = keepmin ? fminf(s, o) : fmaxf(s, o);
            }
        }
        const float tau21 = __shfl(s, 20);
        const float sqn = sqB[(b << 11) + nrow];
        const float margin = 3e-4f * sqrtf(fmaxf(sqn, 0.f)) * Rmax + 1e-12f;
        const float cutoff = tau21 + 2.f * margin;
        int cnt = 0;
        int* cl = &cand[(wave * 2 + rr) * 64];
#pragma unroll
        for (int pass = 0; pass < 2; ++pass) {
#pragma unroll
            for (int j = 0; j < 16; ++j) {
                bool p = (v[pass][rr][j] <= cutoff);
                unsigned long long mask = __ballot(p);
                if (p) {
                    int pos = cnt + (int)__popcll(mask & ((1ull << lane) - 1ull));
                    if (pos < 64)
                        cl[pos] = pass * 1024 + lane * 4 + (j & 3) + ((j >> 2) << 8);
                }
                cnt += (int)__popcll(mask);
            }
        }
        cntk[rr] = (cnt > 64) ? 64 : cnt;
    }

    // ---- refine with exact fp32 (ascending-c fmaf chain, Xt contiguous) ----
#pragma unroll 1
    for (int rr = 0; rr < 2; ++rr) {
        const int nrow = n0 + wave * 2 + rr;
        const int cnt = cntk[rr];
        const float* __restrict__ xn = &Xt[((size_t)(b * N + nrow)) << 6];
        unsigned long long key = ~0ull;
        if (lane < cnt) {
            const int m = cand[(wave * 2 + rr) * 64 + lane];
            const float* __restrict__ xm = &Xt[((size_t)(b * N + m)) << 6];
            float acc = 0.f;
#pragma unroll
            for (int q = 0; q < 16; ++q) {
                float4 a4 = *(const float4*)&xn[q * 4];
                float4 b4 = *(const float4*)&xm[q * 4];
                acc = fmaf(a4.x, b4.x, acc);
                acc = fmaf(a4.y, b4.y, acc);
                acc = fmaf(a4.z, b4.z, acc);
                acc = fmaf(a4.w, b4.w, acc);
            }
            const float d = sqB[(b << 11) + m] - 2.f * acc;
            key = ((unsigned long long)fenc(d) << 32) | (unsigned)m;
        }
#pragma unroll
        for (int k = 2; k <= 64; k <<= 1) {
#pragma unroll
            for (int j = k >> 1; j >= 1; j >>= 1) {
                unsigned long long o = __shfl_xor(key, j);
                bool keepmin = (((lane & j) == 0) == ((lane & k) == 0));
                unsigned long long mn = u64min(key, o);
                key = keepmin ? mn : ((key ^ o) ^ mn);
            }
        }
        // rank 0 is the self column (drop-first == argsort[:,1:21])
        if (lane >= 1 && lane < 21)
            Iout[(b * N + nrow) * K + (lane - 1)] = (int)(unsigned)(key & 0xffffffffu);
    }
}

// ---------------------------------------------------------------------------
// select0: layer-0 (C=3) — scores inline, register topk (fp32-exact).
// ---------------------------------------------------------------------------
__global__ __launch_bounds__(256) void select0_kernel(const float* __restrict__ X,
                                                      int* __restrict__ Iout) {
    const int N = NPTS, K = 20;
    __shared__ unsigned long long cand[4][64];
    const int w = threadIdx.x >> 6, lane = threadIdx.x & 63;
    const int rowg = blockIdx.x * 4 + w;
    const int b = rowg >> 11, n = rowg & 2047;
    const float* __restrict__ Xb = X + (size_t)b * 3 * N;
    const float xr = Xb[n], yr = Xb[N + n], zr = Xb[2 * N + n];
    const float INF = __builtin_inff();
    float v[32];
#pragma unroll
    for (int q = 0; q < 8; ++q) {
        const int base = lane * 4 + q * 256;
        const float4 xm = *(const float4*)&Xb[base];
        const float4 ym = *(const float4*)&Xb[N + base];
        const float4 zm = *(const float4*)&Xb[2 * N + base];
        float mx[4] = {xm.x, xm.y, xm.z, xm.w};
        float my[4] = {ym.x, ym.y, ym.z, ym.w};
        float mz[4] = {zm.x, zm.y, zm.z, zm.w};
#pragma unroll
        for (int j = 0; j < 4; ++j) {
            float sq = mx[j] * mx[j] + my[j] * my[j] + mz[j] * mz[j];
            float dot = xr * mx[j] + yr * my[j] + zr * mz[j];
            float d = sq - 2.f * dot;
            v[q * 4 + j] = (base + j == n) ? INF : d;
        }
    }
    topk20(v, &cand[w][0], lane, Iout, (b * N + n) * K);
}

// ---------------------------------------------------------------------------
// U/T GEMMs (unchanged).
// ---------------------------------------------------------------------------
template<int F, int C>
__global__ __launch_bounds__(256) void ut_kernel(const float* __restrict__ X, int bs,
                                                 const float* __restrict__ W,
                                                 const float* __restrict__ bias,
                                                 float* __restrict__ U, float* __restrict__ T) {
    const int N = NPTS;
    __shared__ float Ws2[64][C + 1];
    __shared__ float Wsd[64][C + 1];
    const int n0 = blockIdx.x * 64, f0 = blockIdx.y * 64, b = blockIdx.z;
    const int tid = threadIdx.x;
    for (int i = tid; i < 64 * C; i += 256) {
        int ff = i / C, c = i - ff * C;
        float w1 = W[(f0 + ff) * (2 * C) + c];
        float w2 = W[(f0 + ff) * (2 * C) + C + c];
        Ws2[ff][c] = w2;
        Wsd[ff][c] = w1 - w2;
    }
    __syncthreads();
    const int nt = tid & 15, fg = tid >> 4;
    const float* __restrict__ Xb = X + (size_t)b * bs;
    float au[4][4], av[4][4];
#pragma unroll
    for (int i = 0; i < 4; ++i)
#pragma unroll
        for (int j = 0; j < 4; ++j) { au[i][j] = 0.f; av[i][j] = 0.f; }
#pragma unroll 4
    for (int c = 0; c < C; ++c) {
        const float4 xv = *(const float4*)&Xb[(size_t)c * N + n0 + nt * 4];
#pragma unroll
        for (int fi = 0; fi < 4; ++fi) {
            float w2v = Ws2[fg * 4 + fi][c];
            float wdv = Wsd[fg * 4 + fi][c];
            au[fi][0] += w2v * xv.x; au[fi][1] += w2v * xv.y;
            au[fi][2] += w2v * xv.z; au[fi][3] += w2v * xv.w;
            av[fi][0] += wdv * xv.x; av[fi][1] += wdv * xv.y;
            av[fi][2] += wdv * xv.z; av[fi][3] += wdv * xv.w;
        }
    }
#pragma unroll
    for (int ni = 0; ni < 4; ++ni) {
        int n = n0 + nt * 4 + ni;
        float4 uv = make_float4(au[0][ni], au[1][ni], au[2][ni], au[3][ni]);
        *(float4*)&U[((size_t)b * N + n) * F + f0 + fg * 4] = uv;
    }
#pragma unroll
    for (int fi = 0; fi < 4; ++fi) {
        int f = f0 + fg * 4 + fi;
        float bv = bias[f];
        float4 tv = make_float4(av[fi][0] + bv, av[fi][1] + bv, av[fi][2] + bv, av[fi][3] + bv);
        *(float4*)&T[((size_t)b * F + f) * N + n0 + nt * 4] = tv;
    }
}

// ---------------------------------------------------------------------------
// Gather-max: block = 32 points x 8 f-groups. Writes fp32 Hc slice (optional),
// bf16 hi/lo into Ht[b][n][320] at hoff, and (for F=64 layers) the fp32
// transposed Xt[b][n][64] used by the next knnmfma's exact refine.
// ---------------------------------------------------------------------------
template<int F, bool WRITE_F32, bool WRITE_XT>
__global__ __launch_bounds__(256) void gathermax_kernel(const float* __restrict__ U,
                                                        const float* __restrict__ T,
                                                        const int* __restrict__ idx,
                                                        float* __restrict__ Y, int bsY,
                                                        unsigned short* __restrict__ HtH,
                                                        unsigned short* __restrict__ HtL,
                                                        int hoff,
                                                        float* __restrict__ Xt) {
    const int N = NPTS, K = 20, FG = F / 8;
    __shared__ int sidx[32 * 20];
    const int b = blockIdx.y, n0 = blockIdx.x * 32, tid = threadIdx.x;
    const int p = tid >> 3, fg = tid & 7;
    for (int t = tid; t < 32 * K; t += 256) sidx[t] = idx[(b * N + n0) * K + t];
    __syncthreads();
    const int n = n0 + p;
    const float* __restrict__ Ub = U + (size_t)b * N * F;
    const int fbase = fg * FG;
    float mx[FG];
#pragma unroll
    for (int i = 0; i < FG; ++i) mx[i] = -__builtin_inff();
#pragma unroll 4
    for (int j = 0; j < K; ++j) {
        const int r = sidx[p * K + j];
        const float4* up = (const float4*)&Ub[(size_t)r * F + fbase];
#pragma unroll
        for (int q = 0; q < FG / 4; ++q) {
            float4 a = up[q];
            mx[q * 4 + 0] = fmaxf(mx[q * 4 + 0], a.x);
            mx[q * 4 + 1] = fmaxf(mx[q * 4 + 1], a.y);
            mx[q * 4 + 2] = fmaxf(mx[q * 4 + 2], a.z);
            mx[q * 4 + 3] = fmaxf(mx[q * 4 + 3], a.w);
        }
    }
    float val[FG];
#pragma unroll
    for (int i = 0; i < FG; ++i) {
        const int f = fbase + i;
        val[i] = T[((size_t)b * F + f) * N + n] + mx[i];
        if (WRITE_F32) Y[(size_t)b * bsY + (size_t)f * N + n] = val[i];
    }
    if (WRITE_XT) {
        float* xp = &Xt[(((size_t)(b * N + n)) << 6) + fbase];
#pragma unroll
        for (int q = 0; q < FG / 4; ++q)
            *(float4*)&xp[q * 4] = *(const float4*)&val[q * 4];
    }
    unsigned short hs[FG], ls[FG];
#pragma unroll
    for (int i = 0; i < FG; ++i) {
        unsigned short h = f2bf(val[i]);
        hs[i] = h;
        ls[i] = f2bf(val[i] - bf2f(h));
    }
    const size_t hb = ((size_t)b * N + n) * 320 + hoff + fbase;
#pragma unroll
    for (int q = 0; q < FG / 8; ++q) {
        *(int4*)&HtH[hb + q * 8] = *(const int4*)&hs[q * 8];
        *(int4*)&HtL[hb + q * 8] = *(const int4*)&ls[q * 8];
    }
}

// ---------------------------------------------------------------------------
// conv0_w -> bf16 hi/lo split.
// ---------------------------------------------------------------------------
__global__ __launch_bounds__(256) void wsplit_kernel(const float* __restrict__ W,
                                                     unsigned short* __restrict__ WH,
                                                     unsigned short* __restrict__ WL) {
    const int e = blockIdx.x * 256 + threadIdx.x;
    float w = W[e];
    unsigned short h = f2bf(w);
    WH[e] = h;
    WL[e] = f2bf(w - bf2f(h));
}

// ---------------------------------------------------------------------------
// conv0 + global max via bf16x3 MFMA (unchanged, HW-verified in round 5).
// ---------------------------------------------------------------------------
__global__ __launch_bounds__(256) void conv0mfma_kernel(const unsigned short* __restrict__ HtH,
                                                        const unsigned short* __restrict__ HtL,
                                                        const unsigned short* __restrict__ WH,
                                                        const unsigned short* __restrict__ WL,
                                                        unsigned* __restrict__ M) {
    const int N = NPTS;
    __shared__ unsigned short HsH[64][40], HsL[64][40], WsH[128][40], WsL[128][40];
    const int n0 = blockIdx.x * 64, f0 = blockIdx.y * 128, b = blockIdx.z;
    const int tid = threadIdx.x;
    const int wave = tid >> 6, lane = tid & 63;
    const int wm = wave & 1, wf = wave >> 1;
    const int row = lane & 15, quad = lane >> 4;
    f32x4 acc[2][4];
#pragma unroll
    for (int i = 0; i < 2; ++i)
#pragma unroll
        for (int j = 0; j < 4; ++j) acc[i][j] = (f32x4){0.f, 0.f, 0.f, 0.f};

    const int hn = tid >> 2, hq = tid & 3;
    const int wfr = tid >> 1, wq = tid & 1;

    for (int c0 = 0; c0 < 320; c0 += 32) {
        {
            const size_t src = ((size_t)b * N + n0 + hn) * 320 + c0 + hq * 8;
            *(int4*)&HsH[hn][hq * 8] = *(const int4*)&HtH[src];
            *(int4*)&HsL[hn][hq * 8] = *(const int4*)&HtL[src];
        }
        {
            const size_t src = (size_t)(f0 + wfr) * 320 + c0 + wq * 16;
            *(int4*)&WsH[wfr][wq * 16]     = *(const int4*)&WH[src];
            *(int4*)&WsH[wfr][wq * 16 + 8] = *(const int4*)&WH[src + 8];
            *(int4*)&WsL[wfr][wq * 16]     = *(const int4*)&WL[src];
            *(int4*)&WsL[wfr][wq * 16 + 8] = *(const int4*)&WL[src + 8];
        }
        __syncthreads();
        bf16x8 aH[2], aL[2];
#pragma unroll
        for (int mt = 0; mt < 2; ++mt) {
            aH[mt] = *(const bf16x8*)&HsH[wm * 32 + mt * 16 + row][quad * 8];
            aL[mt] = *(const bf16x8*)&HsL[wm * 32 + mt * 16 + row][quad * 8];
        }
#pragma unroll
        for (int nt = 0; nt < 4; ++nt) {
            bf16x8 bH = *(const bf16x8*)&WsH[wf * 64 + nt * 16 + row][quad * 8];
            bf16x8 bL = *(const bf16x8*)&WsL[wf * 64 + nt * 16 + row][quad * 8];
#pragma unroll
            for (int mt = 0; mt < 2; ++mt) {
                acc[mt][nt] = __builtin_amdgcn_mfma_f32_16x16x32_bf16(aH[mt], bH, acc[mt][nt], 0, 0, 0);
                acc[mt][nt] = __builtin_amdgcn_mfma_f32_16x16x32_bf16(aH[mt], bL, acc[mt][nt], 0, 0, 0);
                acc[mt][nt] = __builtin_amdgcn_mfma_f32_16x16x32_bf16(aL[mt], bH, acc[mt][nt], 0, 0, 0);
            }
        }
        __syncthreads();
    }
#pragma unroll
    for (int nt = 0; nt < 4; ++nt) {
        float m = acc[0][nt][0];
#pragma unroll
        for (int r = 1; r < 4; ++r) m = fmaxf(m, acc[0][nt][r]);
#pragma unroll
        for (int r = 0; r < 4; ++r) m = fmaxf(m, acc[1][nt][r]);
        m = fmaxf(m, __shfl_down(m, 16));
        m = fmaxf(m, __shfl_down(m, 32));
        if (quad == 0)
            atomicMax(&M[(b << 10) + f0 + wf * 64 + nt * 16 + row], fenc(m));
    }
}

// ---------------------------------------------------------------------------
// Fused head (unchanged).
// ---------------------------------------------------------------------------
__global__ __launch_bounds__(256) void fc_kernel(const unsigned* __restrict__ M,
    const float* __restrict__ cb, const float* __restrict__ cs, const float* __restrict__ ct,
    const float* __restrict__ w0, const float* __restrict__ b0, const float* __restrict__ s0, const float* __restrict__ t0,
    const float* __restrict__ w1, const float* __restrict__ b1, const float* __restrict__ s1, const float* __restrict__ t1,
    const float* __restrict__ w2, const float* __restrict__ b2, const float* __restrict__ s2, const float* __restrict__ t2,
    float* __restrict__ out) {
    __shared__ float g0[1024], g1[512], g2[256];
    const int b = blockIdx.x, tid = threadIdx.x;
    for (int f = tid; f < 1024; f += 256) {
        float z = fdec(M[b * 1024 + f]);
        float g = cs[f] * (z + cb[f]) + ct[f];
        g0[f] = fmaxf(g, 0.f);
    }
    __syncthreads();
    for (int f = tid; f < 512; f += 256) {
        const float4* wp = (const float4*)(w0 + (size_t)f * 1024);
        float acc = 0.f;
#pragma unroll 4
        for (int c = 0; c < 256; ++c) {
            float4 wv = wp[c];
            float4 gv = *(const float4*)&g0[c * 4];
            acc += wv.x * gv.x + wv.y * gv.y + wv.z * gv.z + wv.w * gv.w;
        }
        float g = s0[f] * (acc + b0[f]) + t0[f];
        g1[f] = fmaxf(g, 0.f);
    }
    __syncthreads();
    if (tid < 256) {
        const float4* wp = (const float4*)(w1 + (size_t)tid * 512);
        float acc = 0.f;
#pragma unroll 4
        for (int c = 0; c < 128; ++c) {
            float4 wv = wp[c];
            float4 gv = *(const float4*)&g1[c * 4];
            acc += wv.x * gv.x + wv.y * gv.y + wv.z * gv.z + wv.w * gv.w;
        }
        float g = s1[tid] * (acc + b1[tid]) + t1[tid];
        g2[tid] = fmaxf(g, 0.f);
    }
    __syncthreads();
    if (tid < 40) {
        const float4* wp = (const float4*)(w2 + (size_t)tid * 256);
        float acc = 0.f;
#pragma unroll 4
        for (int c = 0; c < 64; ++c) {
            float4 wv = wp[c];
            float4 gv = *(const float4*)&g2[c * 4];
            acc += wv.x * gv.x + wv.y * gv.y + wv.z * gv.z + wv.w * gv.w;
        }
        float g = s2[tid] * (acc + b2[tid]) + t2[tid];
        out[b * 40 + tid] = fmaxf(g, 0.f);
    }
}

// ---------------------------------------------------------------------------
extern "C" void kernel_launch(void* const* d_in, const int* in_sizes, int n_in,
                              void* d_out, int out_size, void* d_ws, size_t ws_size,
                              hipStream_t stream) {
    const float* x       = (const float*)d_in[0];
    const float* ec0_w   = (const float*)d_in[1];
    const float* ec0_b   = (const float*)d_in[2];
    const float* ec1_w   = (const float*)d_in[3];
    const float* ec1_b   = (const float*)d_in[4];
    const float* ec2_w   = (const float*)d_in[5];
    const float* ec2_b   = (const float*)d_in[6];
    const float* ec3_w   = (const float*)d_in[7];
    const float* ec3_b   = (const float*)d_in[8];
    const float* conv0_w = (const float*)d_in[9];
    const float* conv0_b = (const float*)d_in[10];
    const float* conv0_s = (const float*)d_in[11];
    const float* conv0_t = (const float*)d_in[12];
    const float* fc0_w   = (const float*)d_in[13];
    const float* fc0_b   = (const float*)d_in[14];
    const float* fc0_s   = (const float*)d_in[15];
    const float* fc0_t   = (const float*)d_in[16];
    const float* fc1_w   = (const float*)d_in[17];
    const float* fc1_b   = (const float*)d_in[18];
    const float* fc1_s   = (const float*)d_in[19];
    const float* fc1_t   = (const float*)d_in[20];
    const float* fc2_w   = (const float*)d_in[21];
    const float* fc2_b   = (const float*)d_in[22];
    const float* fc2_s   = (const float*)d_in[23];
    const float* fc2_t   = (const float*)d_in[24];
    float* out = (float*)d_out;

    char* ws = (char*)d_ws;
    const int B = 16, N = NPTS;
    float* Hc   = (float*)(ws + 0);            // [16][320][2048]  41,943,040 B
    float* U    = (float*)(ws + 41943040);     // [16][2048][128]  16,777,216 B
    float* T    = (float*)(ws + 58720256);     // [16][128][2048]  16,777,216 B
    int*   I    = (int*)  (ws + 75497472);     // [16][2048][20]    2,621,440 B
    unsigned* M = (unsigned*)(ws + 78118912);  // [16][1024]           65,536 B
    unsigned short* W_hi = (unsigned short*)(ws + 78184448);  //  655,360 B
    unsigned short* W_lo = (unsigned short*)(ws + 78839808);  //  655,360 B
    unsigned short* HtH  = (unsigned short*)(ws + 79495168);  // [16][2048][320] 20,971,520 B
    unsigned short* HtL  = (unsigned short*)(ws + 100466688); // [16][2048][320] 20,971,520 B
    float* sqb  = (float*)(ws + 121438208);    // [16][2048]          131,072 B
    unsigned* Rsq = (unsigned*)(ws + 121569280); // [16]                   64 B
    float* Xt   = (float*)(ws + 121569344);    // [16][2048][64]    8,388,608 B (per-layer, overwritten)
    // end: 129,957,952 B

    (void)hipFuncSetAttribute((const void*)knnmfma_kernel,
                              hipFuncAttributeMaxDynamicSharedMemorySize, 69888);

    dim3 blk(256);
    const int bsX0 = 3 * N, bsH = 320 * N;

    wsplit_kernel<<<dim3(1024 * 320 / 256), blk, 0, stream>>>(conv0_w, W_hi, W_lo);

    // ---- Layer 0 (C=3 -> F=64) ----
    select0_kernel<<<dim3(B * N / 4), blk, 0, stream>>>(x, I);
    ut_kernel<64, 3><<<dim3(N / 64, 1, B), blk, 0, stream>>>(x, bsX0, ec0_w, ec0_b, U, T);
    gathermax_kernel<64, true, true><<<dim3(N / 32, B), blk, 0, stream>>>(
        U, T, I, Hc, bsH, HtH, HtL, 0, Xt);

    // ---- Layers 1..3 (C=64): MFMA-approx KNN + exact fp32 refine (Xt) ----
    const float* Xin[3] = {Hc, Hc + (size_t)64 * N, Hc + (size_t)128 * N};
    const float* ecw[3] = {ec1_w, ec2_w, ec3_w};
    const float* ecb[3] = {ec1_b, ec2_b, ec3_b};
    for (int L = 0; L < 3; ++L) {
        (void)hipMemsetAsync(Rsq, 0, B * sizeof(unsigned), stream);
        sqmax_kernel<<<dim3(N / 256, B), blk, 0, stream>>>(Xin[L], bsH, sqb, Rsq);
        knnmfma_kernel<<<dim3(N / 16, B), dim3(512), 69888, stream>>>(
            HtH, HtL, 64 * L, Xt, sqb, Rsq, I);
        if (L < 2) {
            ut_kernel<64, 64><<<dim3(N / 64, 1, B), blk, 0, stream>>>(Xin[L], bsH, ecw[L], ecb[L], U, T);
            gathermax_kernel<64, true, true><<<dim3(N / 32, B), blk, 0, stream>>>(
                U, T, I, Hc + (size_t)(64 * (L + 1)) * N, bsH, HtH, HtL, 64 * (L + 1), Xt);
        } else {
            ut_kernel<128, 64><<<dim3(N / 64, 2, B), blk, 0, stream>>>(Xin[L], bsH, ecw[L], ecb[L], U, T);
            gathermax_kernel<128, false, false><<<dim3(N / 32, B), blk, 0, stream>>>(
                U, T, I, Hc + (size_t)192 * N, bsH, HtH, HtL, 192, Xt);
        }
    }

    // ---- conv0 + global max (bf16x3 MFMA) ----
    (void)hipMemsetAsync(M, 0, B * 1024 * sizeof(unsigned), stream);
    conv0mfma_kernel<<<dim3(N / 64, 1024 / 128, B), blk, 0, stream>>>(HtH, HtL, W_hi, W_lo, M);

    // ---- head ----
    fc_kernel<<<dim3(B), blk, 0, stream>>>(M, conv0_b, conv0_s, conv0_t,
                                           fc0_w, fc0_b, fc0_s, fc0_t,
                                           fc1_w, fc1_b, fc1_s, fc1_t,
                                           fc2_w, fc2_b, fc2_s, fc2_t, out);
}